// Round 7
// baseline (47526.276 us; speedup 1.0000x reference)
//
#include <hip/hip_runtime.h>

// LSTM encoder, fully fused persistent kernel.
// r7 = r3 skeleton (wave-per-gate, LDS C-spill, 128-thread gate phase,
// coalesced publish, SYNC2/3/4) + XCD-LOCAL groups (self-discovered via
// HW_REG_XCC_ID + startup slot claim) + h exchange through the XCD's shared
// L2 with sc0 inline-asm loads/stores (tag-in-data protocol unchanged) +
// x register-prefetch/OX double-buffer (SYNC1 gone) + counted vmcnt poll wait.
//
// Placement proof: cooperative launch guarantees co-residency; 147.7 KB LDS
// allows max 1 WG/CU; 256 WGs on 256 CUs => exactly 1/CU => exactly 32 WGs
// per XCD. Each WG claims slot = atomicAdd(slotcnt[xcd]) in [0,32).
// Group = XCD => all h traffic is intra-XCD, served by the shared L2
// (CDNA L1 is write-through; sc0 loads bypass L1, read L2 directly).
// Escalation: after 200 retry rounds fall back to sc1 (agent) loads --
// same-XCD L2 serves those too, so any sc0 surprise = slow pass, not hang.

typedef float  f32x4  __attribute__((ext_vector_type(4)));
typedef __bf16 bf16x8 __attribute__((ext_vector_type(8)));
typedef unsigned short u16x4 __attribute__((ext_vector_type(4)));
typedef unsigned long long u64;

#define TSEQ 512
#define INDIM 300
#define HID 512
#define ESC_ROUNDS 200

// LDS byte offsets
#define OWH 0          // W_hh slice: 64 rows x 1024B
#define OWI 65536      // W_ih slice: 64 rows x 640B (k>=300 zero)
#define OH  106496     // h tile: 16 rows x 1024B (batches 8..15 zero)
#define OX0 122880     // x tile buf0: 16 rows x 640B (pads zero)
#define OX1 133120     // x tile buf1
#define ORED 143360    // C spill: 64*17 f32 = 4352B
#define LDSZ 147712

__device__ __forceinline__ unsigned short f2bf(float f) {
    union { float f; unsigned u; } v; v.f = f;
    unsigned r = v.u + 0x7fffu + ((v.u >> 16) & 1u);  // RNE
    return (unsigned short)(r >> 16);
}
__device__ __forceinline__ float fsigmoid(float x) {
    return 1.0f / (1.0f + __expf(-x));
}
__device__ __forceinline__ float ftanh(float x) {
    float e = __expf(2.0f * x);
    return 1.0f - 2.0f / (e + 1.0f);
}

extern "C" __global__ __launch_bounds__(256, 1) void lstm_fused(
    const float* __restrict__ inputs,   // [512][64][300]
    const float* __restrict__ Wih,      // [2048][300]
    const float* __restrict__ Whh,      // [2048][512]
    const float* __restrict__ bih,      // [2048]
    const float* __restrict__ bhh,      // [2048]
    unsigned int* __restrict__ hcomm,   // [2][64][512] (tag<<16)|bf16
    unsigned int* __restrict__ slotcnt, // [8] per-XCD slot counters
    float* __restrict__ out)            // [64][512]
{
    __shared__ __align__(16) char lds[LDSZ];
    __shared__ int slot_sh;

    const int tid = threadIdx.x;

    // ---- discover XCD, claim slot within it ----
    int xcd;
    asm("s_getreg_b32 %0, hwreg(HW_REG_XCC_ID)" : "=s"(xcd));
    xcd &= 7;
    if (tid == 0) slot_sh = (int)atomicAdd(&slotcnt[xcd], 1u);

    // ---- zero pad-bearing LDS [OWI, LDSZ) = 82176 B = 5136 x 16B ----
    {
        f32x4 z = {0.0f, 0.0f, 0.0f, 0.0f};
        for (int n = 0; n < 21; ++n) {
            int i = n * 256 + tid;
            if (i < 5136)
                *reinterpret_cast<f32x4*>(lds + OWI + i * 16) = z;
        }
    }
    __syncthreads();
    const int grp = xcd;            // group = physical XCD
    const int mw  = slot_sh & 31;   // 0..31 within the XCD

    // ---- stage W_hh slice (bf16, XOR-swizzled); wave = gate ----
    for (int n = 0; n < 32; ++n) {
        int i  = n * 256 + tid;
        int r  = i >> 7;
        int ic = i & 127;
        int q = r >> 4, jj = r & 15;
        const float4 w = *reinterpret_cast<const float4*>(
            Whh + ((size_t)(q * HID + mw * 16 + jj) * HID + ic * 4));
        u16x4 p = {f2bf(w.x), f2bf(w.y), f2bf(w.z), f2bf(w.w)};
        *reinterpret_cast<u16x4*>(lds + OWH + r * 1024 +
                                  ((ic * 8) ^ ((r & 7) << 4))) = p;
    }
    // ---- stage W_ih slice ----
    for (int n = 0; n < 19; ++n) {
        int i = n * 256 + tid;
        if (i < 4800) {
            int r  = i / 75;
            int ic = i - r * 75;
            int q = r >> 4, jj = r & 15;
            const float4 w = *reinterpret_cast<const float4*>(
                Wih + ((size_t)(q * HID + mw * 16 + jj) * INDIM + ic * 4));
            u16x4 p = {f2bf(w.x), f2bf(w.y), f2bf(w.z), f2bf(w.w)};
            *reinterpret_cast<u16x4*>(lds + OWI + r * 640 +
                                      ((ic * 8) ^ ((r & 7) << 4))) = p;
        }
    }

    // ---- per-thread MFMA roles ----
    const int lane = tid & 63;
    const int wv   = tid >> 6;
    const int arow = wv * 16 + (lane & 15);
    const int kb16 = (lane >> 4) << 4;
    const int amask = (arow & 7) << 4;
    const int aoffh = arow * 1024;
    const int aoffi = arow * 640;
    const int bcol  = lane & 15;
    const int bmask = (bcol & 7) << 4;
    const int boffh = bcol * 1024;
    const int boffi = bcol * 640;

    // assembly roles (tid < 128)
    const int aj = tid & 15;
    const int ab = tid >> 4;
    float bias0 = 0.f, bias1 = 0.f, bias2 = 0.f, bias3 = 0.f;
    if (tid < 128) {
        int hidx = mw * 16 + aj;
        bias0 = bih[0 * HID + hidx] + bhh[0 * HID + hidx];
        bias1 = bih[1 * HID + hidx] + bhh[1 * HID + hidx];
        bias2 = bih[2 * HID + hidx] + bhh[2 * HID + hidx];
        bias3 = bih[3 * HID + hidx] + bhh[3 * HID + hidx];
    }
    float cst = 0.0f;

    // x prefetch decomposition
    const int i0 = tid,       b0 = i0 / 75, c0 = i0 - b0 * 75;
    const int i1 = 256 + tid, b1 = i1 / 75, c1 = i1 - b1 * 75;
    const int i2 = 512 + tid, b2 = i2 / 75, c2 = i2 - b2 * 75;
    const bool has2 = (i2 < 600);

    float* red = reinterpret_cast<float*>(lds + ORED);

    // ---- prologue: stage x_0 into OX0 ----
    {
        const float* xb = inputs + (size_t)(grp * 8) * INDIM;
        float4 v0 = *reinterpret_cast<const float4*>(xb + (size_t)b0 * INDIM + c0 * 4);
        float4 v1 = *reinterpret_cast<const float4*>(xb + (size_t)b1 * INDIM + c1 * 4);
        u16x4 p0 = {f2bf(v0.x), f2bf(v0.y), f2bf(v0.z), f2bf(v0.w)};
        u16x4 p1 = {f2bf(v1.x), f2bf(v1.y), f2bf(v1.z), f2bf(v1.w)};
        *reinterpret_cast<u16x4*>(lds + OX0 + b0 * 640 + ((c0 * 8) ^ ((b0 & 7) << 4))) = p0;
        *reinterpret_cast<u16x4*>(lds + OX0 + b1 * 640 + ((c1 * 8) ^ ((b1 & 7) << 4))) = p1;
        if (has2) {
            float4 v2 = *reinterpret_cast<const float4*>(xb + (size_t)b2 * INDIM + c2 * 4);
            u16x4 p2 = {f2bf(v2.x), f2bf(v2.y), f2bf(v2.z), f2bf(v2.w)};
            *reinterpret_cast<u16x4*>(lds + OX0 + b2 * 640 + ((c2 * 8) ^ ((b2 & 7) << 4))) = p2;
        }
    }
    __syncthreads();   // weights + x_0 staged

#pragma unroll 1
    for (int t = 0; t < TSEQ; ++t) {
        const char* oxc = lds + OX0 + (t & 1) * 10240;

        // ---- (1) issue 8 h-poll loads, sc0 (L2-coherent, L1-bypass) ----
        u64 hv[8];
        const u64* hc = reinterpret_cast<const u64*>(
            hcomm + (size_t)(t & 1) * 32768) + (size_t)grp * 2048 + tid;
        if (t > 0) {
#pragma unroll
            for (int b = 0; b < 8; ++b) {
                asm volatile("global_load_dwordx2 %0, %1, off sc0"
                             : "=&v"(hv[b]) : "v"(hc + b * 256) : "memory");
            }
        }

        // ---- (2) issue x_{t+1} global loads (after polls: counted vmcnt) ----
        float4 xv0, xv1, xv2;
        if (t + 1 < TSEQ) {
            const float* xb = inputs + ((size_t)(t + 1) * 64 + grp * 8) * INDIM;
            xv0 = *reinterpret_cast<const float4*>(xb + (size_t)b0 * INDIM + c0 * 4);
            xv1 = *reinterpret_cast<const float4*>(xb + (size_t)b1 * INDIM + c1 * 4);
            if (has2)
                xv2 = *reinterpret_cast<const float4*>(xb + (size_t)b2 * INDIM + c2 * 4);
        }

        // ---- (3) x-part MFMAs (hide poll latency) ----
        f32x4 ac0 = {0.f, 0.f, 0.f, 0.f};
        f32x4 ac1 = {0.f, 0.f, 0.f, 0.f};
        f32x4 ac2 = {0.f, 0.f, 0.f, 0.f};
        f32x4 ac3 = {0.f, 0.f, 0.f, 0.f};
#pragma unroll
        for (int m = 0; m < 10; ++m) {
            bf16x8 a = *reinterpret_cast<const bf16x8*>(
                lds + OWI + aoffi + ((m * 64 + kb16) ^ amask));
            bf16x8 b = *reinterpret_cast<const bf16x8*>(
                oxc + boffi + ((m * 64 + kb16) ^ bmask));
            switch (m & 3) {
                case 0: ac0 = __builtin_amdgcn_mfma_f32_16x16x32_bf16(a, b, ac0, 0, 0, 0); break;
                case 1: ac1 = __builtin_amdgcn_mfma_f32_16x16x32_bf16(a, b, ac1, 0, 0, 0); break;
                case 2: ac2 = __builtin_amdgcn_mfma_f32_16x16x32_bf16(a, b, ac2, 0, 0, 0); break;
                default: ac3 = __builtin_amdgcn_mfma_f32_16x16x32_bf16(a, b, ac3, 0, 0, 0); break;
            }
        }

        // ---- (4) wait polls (counted: leave x loads in flight), check, retry ----
        if (t > 0) {
            if (t + 1 < TSEQ) {
                asm volatile("s_waitcnt vmcnt(3)" ::: "memory");
            } else {
                asm volatile("s_waitcnt vmcnt(0)" ::: "memory");
            }
            __builtin_amdgcn_sched_barrier(0);
            const u64 expect = ((u64)t << 48) | ((u64)t << 16);
            const u64 tmask  = 0xffff0000ffff0000ull;
            unsigned pend = 0;
#pragma unroll
            for (int b = 0; b < 8; ++b)
                if ((hv[b] & tmask) != expect) pend |= 1u << b;
            int rounds = 0;
            while (pend) {
                __builtin_amdgcn_s_sleep(2);
                if (rounds < ESC_ROUNDS) {
#pragma unroll
                    for (int b = 0; b < 8; ++b)
                        if (pend & (1u << b))
                            asm volatile("global_load_dwordx2 %0, %1, off sc0"
                                         : "=&v"(hv[b]) : "v"(hc + b * 256) : "memory");
                    asm volatile("s_waitcnt vmcnt(0)" ::: "memory");
                    __builtin_amdgcn_sched_barrier(0);
                } else {
#pragma unroll
                    for (int b = 0; b < 8; ++b)
                        if (pend & (1u << b))
                            hv[b] = __hip_atomic_load(hc + b * 256, __ATOMIC_RELAXED,
                                                      __HIP_MEMORY_SCOPE_AGENT);
                }
#pragma unroll
                for (int b = 0; b < 8; ++b)
                    if ((hv[b] & tmask) == expect) pend &= ~(1u << b);
                ++rounds;
            }
            // stage h(t) into OH
#pragma unroll
            for (int b = 0; b < 8; ++b) {
                unsigned pk = (unsigned)(hv[b] & 0xffffu) |
                              ((unsigned)((hv[b] >> 32) & 0xffffu) << 16);
                *reinterpret_cast<unsigned*>(
                    lds + OH + b * 1024 + ((tid * 4) ^ ((b & 7) << 4))) = pk;
            }
        }

        // ---- (5) write x_{t+1} into the other OX buffer ----
        if (t + 1 < TSEQ) {
            char* oxn = lds + OX0 + ((t + 1) & 1) * 10240;
            u16x4 p0 = {f2bf(xv0.x), f2bf(xv0.y), f2bf(xv0.z), f2bf(xv0.w)};
            u16x4 p1 = {f2bf(xv1.x), f2bf(xv1.y), f2bf(xv1.z), f2bf(xv1.w)};
            *reinterpret_cast<u16x4*>(oxn + b0 * 640 + ((c0 * 8) ^ ((b0 & 7) << 4))) = p0;
            *reinterpret_cast<u16x4*>(oxn + b1 * 640 + ((c1 * 8) ^ ((b1 & 7) << 4))) = p1;
            if (has2) {
                u16x4 p2 = {f2bf(xv2.x), f2bf(xv2.y), f2bf(xv2.z), f2bf(xv2.w)};
                *reinterpret_cast<u16x4*>(oxn + b2 * 640 + ((c2 * 8) ^ ((b2 & 7) << 4))) = p2;
            }
        }
        __syncthreads();   // SYNC2: h(t)/x(t+1) staged, prior-step reads done

        // ---- (6) h-part MFMAs ----
        if (t > 0) {
#pragma unroll
            for (int m = 0; m < 16; ++m) {
                bf16x8 a = *reinterpret_cast<const bf16x8*>(
                    lds + OWH + aoffh + ((m * 64 + kb16) ^ amask));
                bf16x8 b = *reinterpret_cast<const bf16x8*>(
                    lds + OH + boffh + ((m * 64 + kb16) ^ bmask));
                switch (m & 3) {
                    case 0: ac0 = __builtin_amdgcn_mfma_f32_16x16x32_bf16(a, b, ac0, 0, 0, 0); break;
                    case 1: ac1 = __builtin_amdgcn_mfma_f32_16x16x32_bf16(a, b, ac1, 0, 0, 0); break;
                    case 2: ac2 = __builtin_amdgcn_mfma_f32_16x16x32_bf16(a, b, ac2, 0, 0, 0); break;
                    default: ac3 = __builtin_amdgcn_mfma_f32_16x16x32_bf16(a, b, ac3, 0, 0, 0); break;
                }
            }
        }
        f32x4 accv = (ac0 + ac1) + (ac2 + ac3);

        // ---- (7) spill C (m89 layout: col=lane&15, row=(lane>>4)*4+reg) ----
        {
            int rbase = (wv * 16 + ((lane >> 4) << 2)) * 17 + bcol;
            red[rbase + 0]  = accv.x;
            red[rbase + 17] = accv.y;
            red[rbase + 34] = accv.z;
            red[rbase + 51] = accv.w;
        }
        __syncthreads();   // SYNC3: spill done

        // ---- (8) gates + cell update + coalesced sc0 publish ----
        if (tid < 128) {
            float gi = bias0 + red[(0 * 16 + aj) * 17 + ab];
            float gf = bias1 + red[(1 * 16 + aj) * 17 + ab];
            float gg = bias2 + red[(2 * 16 + aj) * 17 + ab];
            float go = bias3 + red[(3 * 16 + aj) * 17 + ab];
            float ig = fsigmoid(gi);
            float fg = fsigmoid(gf);
            float cg = ftanh(gg);
            float og = fsigmoid(go);
            cst = fg * cst + ig * cg;
            float hv2 = og * ftanh(cst);
            if (t == TSEQ - 1) {
                out[(size_t)(grp * 8 + ab) * HID + mw * 16 + aj] = hv2;
            } else {
                unsigned word = ((unsigned)(t + 1) << 16) | (unsigned)f2bf(hv2);
                unsigned* p = hcomm + (size_t)((t + 1) & 1) * 32768 +
                              (size_t)(grp * 8 + ab) * 512 + mw * 16 + aj;
                asm volatile("global_store_dword %0, %1, off sc0"
                             :: "v"(p), "v"(word) : "memory");
            }
        }
        __syncthreads();   // SYNC4: keeps next-step polls from starting early
    }
}

extern "C" void kernel_launch(void* const* d_in, const int* in_sizes, int n_in,
                              void* d_out, int out_size, void* d_ws, size_t ws_size,
                              hipStream_t stream) {
    const float* inputs = (const float*)d_in[0];
    const float* Wih    = (const float*)d_in[1];
    const float* Whh    = (const float*)d_in[2];
    const float* bih    = (const float*)d_in[3];
    const float* bhh    = (const float*)d_in[4];
    float* out = (float*)d_out;

    unsigned int* hcomm   = (unsigned int*)d_ws;                   // 256 KB
    unsigned int* slotcnt = (unsigned int*)((char*)d_ws + 262144); // 8 u32

    hipMemsetAsync(d_ws, 0, 262144 + 64, stream);

    void* args[] = {(void*)&inputs, (void*)&Wih, (void*)&Whh, (void*)&bih,
                    (void*)&bhh,    (void*)&hcomm, (void*)&slotcnt, (void*)&out};
    hipLaunchCooperativeKernel(reinterpret_cast<void*>(lstm_fused),
                               dim3(256), dim3(256), args, 0, stream);
}

// Round 8
// 1587.677 us; speedup vs baseline: 29.9345x; 29.9345x over previous
//
#include <hip/hip_runtime.h>

// LSTM encoder, fully fused persistent kernel, fence-free dataflow sync.
// r8 = r3 skeleton (proven 1263us) with exactly three repairs:
//  (1) PARALLEL masked poll retry w/ sleep backoff (r3's per-b serialized
//      retry cost ~7 x 700cy/step: all 8 polls share one producer, so b=1..7
//      each burned sleep+reload serially after b=0 resolved).
//  (2) SYNC4 as RAW s_barrier (no vmcnt drain): __syncthreads would stall
//      all waves on the publish store's L3 ack (~600cy); raw barrier lets
//      the store fly while next polls issue. Hazard audit below.
//  (3) x register prefetch + OX double-buffer (x HBM latency off the
//      critical path; SYNC1 deleted).
//
// Hazard audit (SYNC2/SYNC3 = full __syncthreads, SYNC4 = raw s_barrier):
//  OH: staged pre-SYNC2(t); read (h-MFMA ds_read) drained by SYNC3(t);
//      next stage at t+1 happens after rawSYNC4(t) > SYNC3(t).   OK
//  OX[2]: write OX[(t+1)&1] pre-SYNC2(t); read at t+1 post-rawSYNC4(t);
//      rewrite at t+2 post-SYNC2(t+1) by which readers' ds_reads drained. OK
//  red (single): spill pre-SYNC3(t); gates read post-SYNC3(t), drained by
//      SYNC2(t+1); next spill write is post-SYNC2(t+1).          OK
//  raw barrier vs publish store: gates' red ds_reads are consumed into
//      registers before the store value exists (data dependency), so no
//      LDS op can be pending at the raw barrier that a later writer races.
//  hcomm ABA: slot (parity p, tag t+1) overwrites tag t-1. Producer P
//      reaches its publish only after P's polls saw ALL tag-t publishes;
//      consumer C's tag-t publish data-depends on C's tag-(t-1) poll reads
//      of that slot. So C's reads happen-before P's overwrite.    OK

typedef float  f32x4  __attribute__((ext_vector_type(4)));
typedef __bf16 bf16x8 __attribute__((ext_vector_type(8)));
typedef unsigned short u16x4 __attribute__((ext_vector_type(4)));
typedef unsigned long long u64;

#define TSEQ 512
#define INDIM 300
#define HID 512

// LDS byte offsets
#define OWH 0          // W_hh slice: 64 rows x 1024B
#define OWI 65536      // W_ih slice: 64 rows x 640B (k>=300 zero)
#define OH  106496     // h tile: 16 rows x 1024B (batches 8..15 zero)
#define OX0 122880     // x tile buf0: 16 rows x 640B (pads zero)
#define OX1 133120     // x tile buf1
#define ORED 143360    // C spill: 64*17 f32 = 4352B
#define LDSZ 147712

__device__ __forceinline__ unsigned short f2bf(float f) {
    union { float f; unsigned u; } v; v.f = f;
    unsigned r = v.u + 0x7fffu + ((v.u >> 16) & 1u);  // RNE
    return (unsigned short)(r >> 16);
}
__device__ __forceinline__ float fsigmoid(float x) {
    return 1.0f / (1.0f + __expf(-x));
}
__device__ __forceinline__ float ftanh(float x) {
    float e = __expf(2.0f * x);
    return 1.0f - 2.0f / (e + 1.0f);
}

extern "C" __global__ __launch_bounds__(256, 1) void lstm_fused(
    const float* __restrict__ inputs,   // [512][64][300]
    const float* __restrict__ Wih,      // [2048][300]
    const float* __restrict__ Whh,      // [2048][512]
    const float* __restrict__ bih,      // [2048]
    const float* __restrict__ bhh,      // [2048]
    unsigned int* __restrict__ hcomm,   // [2][64][512] (tag<<16)|bf16
    float* __restrict__ out)            // [64][512]
{
    __shared__ __align__(16) char lds[LDSZ];

    const int tid = threadIdx.x;
    const int wg  = blockIdx.x;
    const int grp = wg & 7;
    const int mw  = wg >> 3;

    // ---- zero pad-bearing LDS [OWI, LDSZ) = 82176 B = 5136 x 16B ----
    {
        f32x4 z = {0.0f, 0.0f, 0.0f, 0.0f};
        for (int n = 0; n < 21; ++n) {
            int i = n * 256 + tid;
            if (i < 5136)
                *reinterpret_cast<f32x4*>(lds + OWI + i * 16) = z;
        }
    }
    __syncthreads();

    // ---- stage W_hh slice (bf16, XOR-swizzled); wave = gate ----
    for (int n = 0; n < 32; ++n) {
        int i  = n * 256 + tid;
        int r  = i >> 7;
        int ic = i & 127;
        int q = r >> 4, jj = r & 15;
        const float4 w = *reinterpret_cast<const float4*>(
            Whh + ((size_t)(q * HID + mw * 16 + jj) * HID + ic * 4));
        u16x4 p = {f2bf(w.x), f2bf(w.y), f2bf(w.z), f2bf(w.w)};
        *reinterpret_cast<u16x4*>(lds + OWH + r * 1024 +
                                  ((ic * 8) ^ ((r & 7) << 4))) = p;
    }
    // ---- stage W_ih slice ----
    for (int n = 0; n < 19; ++n) {
        int i = n * 256 + tid;
        if (i < 4800) {
            int r  = i / 75;
            int ic = i - r * 75;
            int q = r >> 4, jj = r & 15;
            const float4 w = *reinterpret_cast<const float4*>(
                Wih + ((size_t)(q * HID + mw * 16 + jj) * INDIM + ic * 4));
            u16x4 p = {f2bf(w.x), f2bf(w.y), f2bf(w.z), f2bf(w.w)};
            *reinterpret_cast<u16x4*>(lds + OWI + r * 640 +
                                      ((ic * 8) ^ ((r & 7) << 4))) = p;
        }
    }

    // ---- per-thread MFMA roles ----
    const int lane = tid & 63;
    const int wv   = tid >> 6;
    const int arow = wv * 16 + (lane & 15);
    const int kb16 = (lane >> 4) << 4;
    const int amask = (arow & 7) << 4;
    const int aoffh = arow * 1024;
    const int aoffi = arow * 640;
    const int bcol  = lane & 15;
    const int bmask = (bcol & 7) << 4;
    const int boffh = bcol * 1024;
    const int boffi = bcol * 640;

    // assembly roles (tid < 128)
    const int aj = tid & 15;
    const int ab = tid >> 4;
    float bias0 = 0.f, bias1 = 0.f, bias2 = 0.f, bias3 = 0.f;
    if (tid < 128) {
        int hidx = mw * 16 + aj;
        bias0 = bih[0 * HID + hidx] + bhh[0 * HID + hidx];
        bias1 = bih[1 * HID + hidx] + bhh[1 * HID + hidx];
        bias2 = bih[2 * HID + hidx] + bhh[2 * HID + hidx];
        bias3 = bih[3 * HID + hidx] + bhh[3 * HID + hidx];
    }
    float cst = 0.0f;

    // x prefetch decomposition
    const int i0 = tid,       b0 = i0 / 75, c0 = i0 - b0 * 75;
    const int i1 = 256 + tid, b1 = i1 / 75, c1 = i1 - b1 * 75;
    const int i2 = 512 + tid, b2 = i2 / 75, c2 = i2 - b2 * 75;
    const bool has2 = (i2 < 600);

    float* red = reinterpret_cast<float*>(lds + ORED);

    // ---- prologue: stage x_0 into OX0 ----
    {
        const float* xb = inputs + (size_t)(grp * 8) * INDIM;
        float4 v0 = *reinterpret_cast<const float4*>(xb + (size_t)b0 * INDIM + c0 * 4);
        float4 v1 = *reinterpret_cast<const float4*>(xb + (size_t)b1 * INDIM + c1 * 4);
        u16x4 p0 = {f2bf(v0.x), f2bf(v0.y), f2bf(v0.z), f2bf(v0.w)};
        u16x4 p1 = {f2bf(v1.x), f2bf(v1.y), f2bf(v1.z), f2bf(v1.w)};
        *reinterpret_cast<u16x4*>(lds + OX0 + b0 * 640 + ((c0 * 8) ^ ((b0 & 7) << 4))) = p0;
        *reinterpret_cast<u16x4*>(lds + OX0 + b1 * 640 + ((c1 * 8) ^ ((b1 & 7) << 4))) = p1;
        if (has2) {
            float4 v2 = *reinterpret_cast<const float4*>(xb + (size_t)b2 * INDIM + c2 * 4);
            u16x4 p2 = {f2bf(v2.x), f2bf(v2.y), f2bf(v2.z), f2bf(v2.w)};
            *reinterpret_cast<u16x4*>(lds + OX0 + b2 * 640 + ((c2 * 8) ^ ((b2 & 7) << 4))) = p2;
        }
    }
    __syncthreads();   // weights + x_0 staged

#pragma unroll 1
    for (int t = 0; t < TSEQ; ++t) {
        const char* oxc = lds + OX0 + (t & 1) * 10240;

        // ---- (1) issue 8 h poll loads FIRST ----
        u64 hv64[8];
        const u64* hc = reinterpret_cast<const u64*>(
            hcomm + (size_t)(t & 1) * 32768) + (size_t)grp * 2048 + tid;
        if (t > 0) {
#pragma unroll
            for (int b = 0; b < 8; ++b)
                hv64[b] = __hip_atomic_load(hc + b * 256, __ATOMIC_RELAXED,
                                            __HIP_MEMORY_SCOPE_AGENT);
        }

        // ---- (2) issue x_{t+1} loads (after polls: check waits vmcnt(3)) ----
        float4 xv0, xv1, xv2;
        if (t + 1 < TSEQ) {
            const float* xb = inputs + ((size_t)(t + 1) * 64 + grp * 8) * INDIM;
            xv0 = *reinterpret_cast<const float4*>(xb + (size_t)b0 * INDIM + c0 * 4);
            xv1 = *reinterpret_cast<const float4*>(xb + (size_t)b1 * INDIM + c1 * 4);
            if (has2)
                xv2 = *reinterpret_cast<const float4*>(xb + (size_t)b2 * INDIM + c2 * 4);
        }

        // ---- (3) x-part MFMAs (hide poll latency) ----
        f32x4 ac0 = {0.f, 0.f, 0.f, 0.f};
        f32x4 ac1 = {0.f, 0.f, 0.f, 0.f};
        f32x4 ac2 = {0.f, 0.f, 0.f, 0.f};
        f32x4 ac3 = {0.f, 0.f, 0.f, 0.f};
#pragma unroll
        for (int m = 0; m < 10; ++m) {
            bf16x8 a = *reinterpret_cast<const bf16x8*>(
                lds + OWI + aoffi + ((m * 64 + kb16) ^ amask));
            bf16x8 b = *reinterpret_cast<const bf16x8*>(
                oxc + boffi + ((m * 64 + kb16) ^ bmask));
            switch (m & 3) {
                case 0: ac0 = __builtin_amdgcn_mfma_f32_16x16x32_bf16(a, b, ac0, 0, 0, 0); break;
                case 1: ac1 = __builtin_amdgcn_mfma_f32_16x16x32_bf16(a, b, ac1, 0, 0, 0); break;
                case 2: ac2 = __builtin_amdgcn_mfma_f32_16x16x32_bf16(a, b, ac2, 0, 0, 0); break;
                default: ac3 = __builtin_amdgcn_mfma_f32_16x16x32_bf16(a, b, ac3, 0, 0, 0); break;
            }
        }

        // ---- (4) PARALLEL masked retry with backoff; stage h ----
        if (t > 0) {
            const u64 expect = ((u64)t << 48) | ((u64)t << 16);
            const u64 tmask  = 0xffff0000ffff0000ull;
            unsigned pend = 0;
#pragma unroll
            for (int b = 0; b < 8; ++b)
                if ((hv64[b] & tmask) != expect) pend |= 1u << b;
            while (pend) {
                __builtin_amdgcn_s_sleep(2);
#pragma unroll
                for (int b = 0; b < 8; ++b)
                    if (pend & (1u << b))
                        hv64[b] = __hip_atomic_load(hc + b * 256, __ATOMIC_RELAXED,
                                                    __HIP_MEMORY_SCOPE_AGENT);
#pragma unroll
                for (int b = 0; b < 8; ++b)
                    if ((hv64[b] & tmask) == expect) pend &= ~(1u << b);
            }
#pragma unroll
            for (int b = 0; b < 8; ++b) {
                unsigned pk = (unsigned)(hv64[b] & 0xffffu) |
                              ((unsigned)((hv64[b] >> 32) & 0xffffu) << 16);
                *reinterpret_cast<unsigned*>(
                    lds + OH + b * 1024 + ((tid * 4) ^ ((b & 7) << 4))) = pk;
            }
        }

        // ---- (5) write x_{t+1} into the other OX buffer ----
        if (t + 1 < TSEQ) {
            char* oxn = lds + OX0 + ((t + 1) & 1) * 10240;
            u16x4 p0 = {f2bf(xv0.x), f2bf(xv0.y), f2bf(xv0.z), f2bf(xv0.w)};
            u16x4 p1 = {f2bf(xv1.x), f2bf(xv1.y), f2bf(xv1.z), f2bf(xv1.w)};
            *reinterpret_cast<u16x4*>(oxn + b0 * 640 + ((c0 * 8) ^ ((b0 & 7) << 4))) = p0;
            *reinterpret_cast<u16x4*>(oxn + b1 * 640 + ((c1 * 8) ^ ((b1 & 7) << 4))) = p1;
            if (has2) {
                u16x4 p2 = {f2bf(xv2.x), f2bf(xv2.y), f2bf(xv2.z), f2bf(xv2.w)};
                *reinterpret_cast<u16x4*>(oxn + b2 * 640 + ((c2 * 8) ^ ((b2 & 7) << 4))) = p2;
            }
        }
        __syncthreads();   // SYNC2: h(t)/x(t+1) staged, prior-step reads done

        // ---- (6) h-part MFMAs ----
        if (t > 0) {
#pragma unroll
            for (int m = 0; m < 16; ++m) {
                bf16x8 a = *reinterpret_cast<const bf16x8*>(
                    lds + OWH + aoffh + ((m * 64 + kb16) ^ amask));
                bf16x8 b = *reinterpret_cast<const bf16x8*>(
                    lds + OH + boffh + ((m * 64 + kb16) ^ bmask));
                switch (m & 3) {
                    case 0: ac0 = __builtin_amdgcn_mfma_f32_16x16x32_bf16(a, b, ac0, 0, 0, 0); break;
                    case 1: ac1 = __builtin_amdgcn_mfma_f32_16x16x32_bf16(a, b, ac1, 0, 0, 0); break;
                    case 2: ac2 = __builtin_amdgcn_mfma_f32_16x16x32_bf16(a, b, ac2, 0, 0, 0); break;
                    default: ac3 = __builtin_amdgcn_mfma_f32_16x16x32_bf16(a, b, ac3, 0, 0, 0); break;
                }
            }
        }
        f32x4 accv = (ac0 + ac1) + (ac2 + ac3);

        // ---- (7) spill C (m89 layout: col=lane&15, row=(lane>>4)*4+reg) ----
        {
            int rbase = (wv * 16 + ((lane >> 4) << 2)) * 17 + bcol;
            red[rbase + 0]  = accv.x;
            red[rbase + 17] = accv.y;
            red[rbase + 34] = accv.z;
            red[rbase + 51] = accv.w;
        }
        __syncthreads();   // SYNC3: spill done

        // ---- (8) gates + cell update + coalesced publish ----
        if (tid < 128) {
            float gi = bias0 + red[(0 * 16 + aj) * 17 + ab];
            float gf = bias1 + red[(1 * 16 + aj) * 17 + ab];
            float gg = bias2 + red[(2 * 16 + aj) * 17 + ab];
            float go = bias3 + red[(3 * 16 + aj) * 17 + ab];
            float ig = fsigmoid(gi);
            float fg = fsigmoid(gf);
            float cg = ftanh(gg);
            float og = fsigmoid(go);
            cst = fg * cst + ig * cg;
            float hv = og * ftanh(cst);
            if (t == TSEQ - 1) {
                out[(size_t)(grp * 8 + ab) * HID + mw * 16 + aj] = hv;
            } else {
                unsigned word = ((unsigned)(t + 1) << 16) | (unsigned)f2bf(hv);
                __hip_atomic_store(
                    hcomm + (size_t)((t + 1) & 1) * 32768 +
                        (size_t)(grp * 8 + ab) * 512 + mw * 16 + aj,
                    word, __ATOMIC_RELAXED, __HIP_MEMORY_SCOPE_AGENT);
            }
        }
        // SYNC4: RAW barrier -- no vmcnt drain, publish store stays in
        // flight while next iteration's polls issue. Hazards audited above.
        __builtin_amdgcn_s_barrier();
    }
}

extern "C" void kernel_launch(void* const* d_in, const int* in_sizes, int n_in,
                              void* d_out, int out_size, void* d_ws, size_t ws_size,
                              hipStream_t stream) {
    const float* inputs = (const float*)d_in[0];
    const float* Wih    = (const float*)d_in[1];
    const float* Whh    = (const float*)d_in[2];
    const float* bih    = (const float*)d_in[3];
    const float* bhh    = (const float*)d_in[4];
    float* out = (float*)d_out;

    unsigned int* hcomm = (unsigned int*)d_ws;   // [2][64][512] u32 = 256 KB

    hipMemsetAsync(hcomm, 0, 2 * 64 * 512 * sizeof(unsigned int), stream);

    void* args[] = {(void*)&inputs, (void*)&Wih, (void*)&Whh, (void*)&bih,
                    (void*)&bhh,    (void*)&hcomm, (void*)&out};
    hipLaunchCooperativeKernel(reinterpret_cast<void*>(lstm_fused),
                               dim3(256), dim3(256), args, 0, stream);
}

// Round 9
// 1542.179 us; speedup vs baseline: 30.8176x; 1.0295x over previous
//
#include <hip/hip_runtime.h>

// LSTM encoder, fully fused persistent kernel — XCD-LOCAL L2 exchange.
// 256 WGs (1/CU, forced by 147.7KB LDS) = 8 XCD-groups x 32 WGs, discovered
// via HW_REG_XCC_ID + slot atomicAdd (pigeonhole: coop launch + 1WG/CU =>
// exactly 32 WGs per XCD). Group g owns batches [8g,8g+8).
//
// Exchange protocol (all intra-XCD, through the shared per-XCD L2):
//   publish: workgroup-relaxed stores (write-through L1 -> L2, ~150cy),
//            s_waitcnt vmcnt(0), raw s_barrier, then per-consumer flag
//            stores flags[grp][cons][mw]=t+1 (32 scattered words).
//   consume: wave0 polls own flag row via global_atomic_or sc0 (atomics
//            execute AT the L2 -> L1-staleness-proof), raw barrier,
//            buffer_inv (vL1 invalidate), plain dwordx2 loads -> fresh L2.
//   belt+braces: every data word still carries (tag<<16)|bf16; stale tags
//            retry (inv+reload), escalating to agent-scope (sc1, L3-probe)
//            loads after K2 rounds; flag poll escalates after K1 rounds.
//            All failure modes = slow pass, not hang (r7 evidence: sc1
//            probes dirty L2 lines eventually).
// Hazard audit: SYNC2/SYNC3 full __syncthreads as r3 (proven); OH single,
// OX double, red single buffers as r8's audit; hcomm parity ABA protected
// by the flag->publish->read dependency chain (consumer's publish is
// value-dependent on its reads; producer's overwrite is flag-gated).

typedef float  f32x4  __attribute__((ext_vector_type(4)));
typedef __bf16 bf16x8 __attribute__((ext_vector_type(8)));
typedef unsigned short u16x4 __attribute__((ext_vector_type(4)));
typedef unsigned long long u64;

#define TSEQ 512
#define INDIM 300
#define HID 512
#define K1_ESC 256
#define K2_ESC 32

// LDS byte offsets
#define OWH 0          // W_hh slice: 64 rows x 1024B
#define OWI 65536      // W_ih slice: 64 rows x 640B (k>=300 zero)
#define OH  106496     // h tile: 16 rows x 1024B (batches 8..15 zero)
#define OX0 122880     // x tile buf0: 16 rows x 640B (pads zero)
#define OX1 133120     // x tile buf1
#define ORED 143360    // C spill: 64*17 f32 = 4352B
#define LDSZ 147712

__device__ __forceinline__ unsigned short f2bf(float f) {
    union { float f; unsigned u; } v; v.f = f;
    unsigned r = v.u + 0x7fffu + ((v.u >> 16) & 1u);  // RNE
    return (unsigned short)(r >> 16);
}
__device__ __forceinline__ float fsigmoid(float x) {
    return 1.0f / (1.0f + __expf(-x));
}
__device__ __forceinline__ float ftanh(float x) {
    float e = __expf(2.0f * x);
    return 1.0f - 2.0f / (e + 1.0f);
}

extern "C" __global__ __launch_bounds__(256, 1) void lstm_fused(
    const float* __restrict__ inputs,   // [512][64][300]
    const float* __restrict__ Wih,      // [2048][300]
    const float* __restrict__ Whh,      // [2048][512]
    const float* __restrict__ bih,      // [2048]
    const float* __restrict__ bhh,      // [2048]
    unsigned int* __restrict__ hcomm,   // [2][64][512] (tag<<16)|bf16
    unsigned int* __restrict__ flags,   // [8][32 cons][32 prod]
    unsigned int* __restrict__ slotcnt, // [8] per-XCD slot counters
    float* __restrict__ out)            // [64][512]
{
    __shared__ __align__(16) char lds[LDSZ];
    __shared__ int slot_sh;

    const int tid = threadIdx.x;

    // ---- discover XCD, claim slot (r7-proven) ----
    int xcd;
    asm("s_getreg_b32 %0, hwreg(HW_REG_XCC_ID)" : "=s"(xcd));
    xcd &= 7;
    if (tid == 0) slot_sh = (int)atomicAdd(&slotcnt[xcd], 1u);

    // ---- zero pad-bearing LDS [OWI, LDSZ) = 82176 B = 5136 x 16B ----
    {
        f32x4 z = {0.0f, 0.0f, 0.0f, 0.0f};
        for (int n = 0; n < 21; ++n) {
            int i = n * 256 + tid;
            if (i < 5136)
                *reinterpret_cast<f32x4*>(lds + OWI + i * 16) = z;
        }
    }
    __syncthreads();
    const int grp = xcd;
    const int mw  = slot_sh & 31;

    // ---- stage W_hh slice (bf16, XOR-swizzled); wave = gate ----
    for (int n = 0; n < 32; ++n) {
        int i  = n * 256 + tid;
        int r  = i >> 7;
        int ic = i & 127;
        int q = r >> 4, jj = r & 15;
        const float4 w = *reinterpret_cast<const float4*>(
            Whh + ((size_t)(q * HID + mw * 16 + jj) * HID + ic * 4));
        u16x4 p = {f2bf(w.x), f2bf(w.y), f2bf(w.z), f2bf(w.w)};
        *reinterpret_cast<u16x4*>(lds + OWH + r * 1024 +
                                  ((ic * 8) ^ ((r & 7) << 4))) = p;
    }
    // ---- stage W_ih slice ----
    for (int n = 0; n < 19; ++n) {
        int i = n * 256 + tid;
        if (i < 4800) {
            int r  = i / 75;
            int ic = i - r * 75;
            int q = r >> 4, jj = r & 15;
            const float4 w = *reinterpret_cast<const float4*>(
                Wih + ((size_t)(q * HID + mw * 16 + jj) * INDIM + ic * 4));
            u16x4 p = {f2bf(w.x), f2bf(w.y), f2bf(w.z), f2bf(w.w)};
            *reinterpret_cast<u16x4*>(lds + OWI + r * 640 +
                                      ((ic * 8) ^ ((r & 7) << 4))) = p;
        }
    }

    // ---- per-thread MFMA roles ----
    const int lane = tid & 63;
    const int wv   = tid >> 6;
    const int arow = wv * 16 + (lane & 15);
    const int kb16 = (lane >> 4) << 4;
    const int amask = (arow & 7) << 4;
    const int aoffh = arow * 1024;
    const int aoffi = arow * 640;
    const int bcol  = lane & 15;
    const int bmask = (bcol & 7) << 4;
    const int boffh = bcol * 1024;
    const int boffi = bcol * 640;

    // assembly roles (tid < 128)
    const int aj = tid & 15;
    const int ab = tid >> 4;
    float bias0 = 0.f, bias1 = 0.f, bias2 = 0.f, bias3 = 0.f;
    if (tid < 128) {
        int hidx = mw * 16 + aj;
        bias0 = bih[0 * HID + hidx] + bhh[0 * HID + hidx];
        bias1 = bih[1 * HID + hidx] + bhh[1 * HID + hidx];
        bias2 = bih[2 * HID + hidx] + bhh[2 * HID + hidx];
        bias3 = bih[3 * HID + hidx] + bhh[3 * HID + hidx];
    }
    float cst = 0.0f;

    // x prefetch decomposition
    const int i0 = tid,       b0 = i0 / 75, c0 = i0 - b0 * 75;
    const int i1 = 256 + tid, b1 = i1 / 75, c1 = i1 - b1 * 75;
    const int i2 = 512 + tid, b2 = i2 / 75, c2 = i2 - b2 * 75;
    const bool has2 = (i2 < 600);

    float* red = reinterpret_cast<float*>(lds + ORED);
    unsigned* myrow = flags + ((size_t)grp * 32 + mw) * 32;  // row I poll

    // ---- prologue: stage x_0 into OX0 ----
    {
        const float* xb = inputs + (size_t)(grp * 8) * INDIM;
        float4 v0 = *reinterpret_cast<const float4*>(xb + (size_t)b0 * INDIM + c0 * 4);
        float4 v1 = *reinterpret_cast<const float4*>(xb + (size_t)b1 * INDIM + c1 * 4);
        u16x4 p0 = {f2bf(v0.x), f2bf(v0.y), f2bf(v0.z), f2bf(v0.w)};
        u16x4 p1 = {f2bf(v1.x), f2bf(v1.y), f2bf(v1.z), f2bf(v1.w)};
        *reinterpret_cast<u16x4*>(lds + OX0 + b0 * 640 + ((c0 * 8) ^ ((b0 & 7) << 4))) = p0;
        *reinterpret_cast<u16x4*>(lds + OX0 + b1 * 640 + ((c1 * 8) ^ ((b1 & 7) << 4))) = p1;
        if (has2) {
            float4 v2 = *reinterpret_cast<const float4*>(xb + (size_t)b2 * INDIM + c2 * 4);
            u16x4 p2 = {f2bf(v2.x), f2bf(v2.y), f2bf(v2.z), f2bf(v2.w)};
            *reinterpret_cast<u16x4*>(lds + OX0 + b2 * 640 + ((c2 * 8) ^ ((b2 & 7) << 4))) = p2;
        }
    }
    __syncthreads();   // weights + x_0 staged

#pragma unroll 1
    for (int t = 0; t < TSEQ; ++t) {
        const char* oxc = lds + OX0 + (t & 1) * 10240;

        // ---- (A) issue x_{t+1} loads into registers ----
        float4 xv0, xv1, xv2;
        if (t + 1 < TSEQ) {
            const float* xb = inputs + ((size_t)(t + 1) * 64 + grp * 8) * INDIM;
            xv0 = *reinterpret_cast<const float4*>(xb + (size_t)b0 * INDIM + c0 * 4);
            xv1 = *reinterpret_cast<const float4*>(xb + (size_t)b1 * INDIM + c1 * 4);
            if (has2)
                xv2 = *reinterpret_cast<const float4*>(xb + (size_t)b2 * INDIM + c2 * 4);
        }

        // ---- (B) x-part MFMAs (peers finish publishing meanwhile) ----
        f32x4 ac0 = {0.f, 0.f, 0.f, 0.f};
        f32x4 ac1 = {0.f, 0.f, 0.f, 0.f};
        f32x4 ac2 = {0.f, 0.f, 0.f, 0.f};
        f32x4 ac3 = {0.f, 0.f, 0.f, 0.f};
#pragma unroll
        for (int m = 0; m < 10; ++m) {
            bf16x8 a = *reinterpret_cast<const bf16x8*>(
                lds + OWI + aoffi + ((m * 64 + kb16) ^ amask));
            bf16x8 b = *reinterpret_cast<const bf16x8*>(
                oxc + boffi + ((m * 64 + kb16) ^ bmask));
            switch (m & 3) {
                case 0: ac0 = __builtin_amdgcn_mfma_f32_16x16x32_bf16(a, b, ac0, 0, 0, 0); break;
                case 1: ac1 = __builtin_amdgcn_mfma_f32_16x16x32_bf16(a, b, ac1, 0, 0, 0); break;
                case 2: ac2 = __builtin_amdgcn_mfma_f32_16x16x32_bf16(a, b, ac2, 0, 0, 0); break;
                default: ac3 = __builtin_amdgcn_mfma_f32_16x16x32_bf16(a, b, ac3, 0, 0, 0); break;
            }
        }

        // ---- (C) flag poll: wave0 lanes<32, L2-executed atomics ----
        if (t > 0 && tid < 32) {
            const unsigned* fp = myrow + tid;   // producer tid's flag for me
            unsigned old = 0;
            int rounds = 0;
            while (true) {
                if (rounds < K1_ESC) {
                    asm volatile("global_atomic_or %0, %1, %2, off sc0\n\t"
                                 "s_waitcnt vmcnt(0)"
                                 : "=v"(old) : "v"(fp), "v"(0u) : "memory");
                } else {
                    old = __hip_atomic_load(fp, __ATOMIC_RELAXED,
                                            __HIP_MEMORY_SCOPE_AGENT);
                }
                if (old >= (unsigned)t) break;
                __builtin_amdgcn_s_sleep(1);
                ++rounds;
            }
        }
        __builtin_amdgcn_s_barrier();   // (D) flags confirmed for all

        // ---- (E) invalidate vL1, read h from local L2, tag-verify ----
        const u64* hc = reinterpret_cast<const u64*>(
            hcomm + (size_t)(t & 1) * 32768) + (size_t)grp * 2048 + tid;
        if (t > 0) {
            u64 hv64[8];
            asm volatile("buffer_inv\n\ts_waitcnt vmcnt(0)" ::: "memory");
            const volatile u64* hcv = reinterpret_cast<const volatile u64*>(hc);
#pragma unroll
            for (int b = 0; b < 8; ++b) hv64[b] = hcv[b * 256];

            const u64 expect = ((u64)t << 48) | ((u64)t << 16);
            const u64 tmask  = 0xffff0000ffff0000ull;
            unsigned pend = 0;
#pragma unroll
            for (int b = 0; b < 8; ++b)
                if ((hv64[b] & tmask) != expect) pend |= 1u << b;
            int r2 = 0;
            while (pend) {
                __builtin_amdgcn_s_sleep(1);
                if (r2 < K2_ESC) {
                    asm volatile("buffer_inv\n\ts_waitcnt vmcnt(0)" ::: "memory");
#pragma unroll
                    for (int b = 0; b < 8; ++b)
                        if (pend & (1u << b)) hv64[b] = hcv[b * 256];
                } else {
#pragma unroll
                    for (int b = 0; b < 8; ++b)
                        if (pend & (1u << b))
                            hv64[b] = __hip_atomic_load(hc + b * 256, __ATOMIC_RELAXED,
                                                        __HIP_MEMORY_SCOPE_AGENT);
                }
#pragma unroll
                for (int b = 0; b < 8; ++b)
                    if ((hv64[b] & tmask) == expect) pend &= ~(1u << b);
                ++r2;
            }
#pragma unroll
            for (int b = 0; b < 8; ++b) {
                unsigned pk = (unsigned)(hv64[b] & 0xffffu) |
                              ((unsigned)((hv64[b] >> 32) & 0xffffu) << 16);
                *reinterpret_cast<unsigned*>(
                    lds + OH + b * 1024 + ((tid * 4) ^ ((b & 7) << 4))) = pk;
            }
        }

        // ---- (F) write x_{t+1} into the other OX buffer ----
        if (t + 1 < TSEQ) {
            char* oxn = lds + OX0 + ((t + 1) & 1) * 10240;
            u16x4 p0 = {f2bf(xv0.x), f2bf(xv0.y), f2bf(xv0.z), f2bf(xv0.w)};
            u16x4 p1 = {f2bf(xv1.x), f2bf(xv1.y), f2bf(xv1.z), f2bf(xv1.w)};
            *reinterpret_cast<u16x4*>(oxn + b0 * 640 + ((c0 * 8) ^ ((b0 & 7) << 4))) = p0;
            *reinterpret_cast<u16x4*>(oxn + b1 * 640 + ((c1 * 8) ^ ((b1 & 7) << 4))) = p1;
            if (has2) {
                u16x4 p2 = {f2bf(xv2.x), f2bf(xv2.y), f2bf(xv2.z), f2bf(xv2.w)};
                *reinterpret_cast<u16x4*>(oxn + b2 * 640 + ((c2 * 8) ^ ((b2 & 7) << 4))) = p2;
            }
        }
        __syncthreads();   // SYNC2: h(t)/x(t+1) staged, prior reads done

        // ---- (H) h-part MFMAs ----
        if (t > 0) {
#pragma unroll
            for (int m = 0; m < 16; ++m) {
                bf16x8 a = *reinterpret_cast<const bf16x8*>(
                    lds + OWH + aoffh + ((m * 64 + kb16) ^ amask));
                bf16x8 b = *reinterpret_cast<const bf16x8*>(
                    lds + OH + boffh + ((m * 64 + kb16) ^ bmask));
                switch (m & 3) {
                    case 0: ac0 = __builtin_amdgcn_mfma_f32_16x16x32_bf16(a, b, ac0, 0, 0, 0); break;
                    case 1: ac1 = __builtin_amdgcn_mfma_f32_16x16x32_bf16(a, b, ac1, 0, 0, 0); break;
                    case 2: ac2 = __builtin_amdgcn_mfma_f32_16x16x32_bf16(a, b, ac2, 0, 0, 0); break;
                    default: ac3 = __builtin_amdgcn_mfma_f32_16x16x32_bf16(a, b, ac3, 0, 0, 0); break;
                }
            }
        }
        f32x4 accv = (ac0 + ac1) + (ac2 + ac3);

        // ---- (I) spill C (m89 layout: col=lane&15, row=(lane>>4)*4+reg) ----
        {
            int rbase = (wv * 16 + ((lane >> 4) << 2)) * 17 + bcol;
            red[rbase + 0]  = accv.x;
            red[rbase + 17] = accv.y;
            red[rbase + 34] = accv.z;
            red[rbase + 51] = accv.w;
        }
        __syncthreads();   // SYNC3: spill done

        // ---- (J) gates + cell update + workgroup-scope publish (L2-local) ----
        if (tid < 128) {
            float gi = bias0 + red[(0 * 16 + aj) * 17 + ab];
            float gf = bias1 + red[(1 * 16 + aj) * 17 + ab];
            float gg = bias2 + red[(2 * 16 + aj) * 17 + ab];
            float go = bias3 + red[(3 * 16 + aj) * 17 + ab];
            float ig = fsigmoid(gi);
            float fg = fsigmoid(gf);
            float cg = ftanh(gg);
            float og = fsigmoid(go);
            cst = fg * cst + ig * cg;
            float hv = og * ftanh(cst);
            if (t == TSEQ - 1) {
                out[(size_t)(grp * 8 + ab) * HID + mw * 16 + aj] = hv;
            } else {
                unsigned word = ((unsigned)(t + 1) << 16) | (unsigned)f2bf(hv);
                __hip_atomic_store(
                    hcomm + (size_t)((t + 1) & 1) * 32768 +
                        (size_t)(grp * 8 + ab) * 512 + mw * 16 + aj,
                    word, __ATOMIC_RELAXED, __HIP_MEMORY_SCOPE_WORKGROUP);
            }
        }

        // ---- (K) order data -> flags, then announce ----
        asm volatile("s_waitcnt vmcnt(0)" ::: "memory");  // stores ACKed by L2
        __builtin_amdgcn_s_barrier();                     // cross-wave order
        if (t + 1 < TSEQ && tid < 32) {
            __hip_atomic_store(
                flags + ((size_t)grp * 32 + tid) * 32 + mw, (unsigned)(t + 1),
                __ATOMIC_RELAXED, __HIP_MEMORY_SCOPE_WORKGROUP);
        }
    }
}

extern "C" void kernel_launch(void* const* d_in, const int* in_sizes, int n_in,
                              void* d_out, int out_size, void* d_ws, size_t ws_size,
                              hipStream_t stream) {
    const float* inputs = (const float*)d_in[0];
    const float* Wih    = (const float*)d_in[1];
    const float* Whh    = (const float*)d_in[2];
    const float* bih    = (const float*)d_in[3];
    const float* bhh    = (const float*)d_in[4];
    float* out = (float*)d_out;

    unsigned int* hcomm   = (unsigned int*)d_ws;                    // 256 KB
    unsigned int* flags   = (unsigned int*)((char*)d_ws + 262144);  // 4 KB
    unsigned int* slotcnt = (unsigned int*)((char*)d_ws + 266240);  // 32 B

    hipMemsetAsync(d_ws, 0, 266240 + 64, stream);

    void* args[] = {(void*)&inputs, (void*)&Wih, (void*)&Whh, (void*)&bih,
                    (void*)&bhh,    (void*)&hcomm, (void*)&flags,
                    (void*)&slotcnt, (void*)&out};
    hipLaunchCooperativeKernel(reinterpret_cast<void*>(lstm_fused),
                               dim3(256), dim3(256), args, 0, stream);
}

// Round 10
// 1401.344 us; speedup vs baseline: 33.9148x; 1.1005x over previous
//
#include <hip/hip_runtime.h>

// LSTM encoder, fully fused persistent kernel — lean XCD-local L2 exchange.
// r10 = r3 skeleton (3 barriers, tag-in-data, polls@top, parallel retry)
// with the exchange moved from L3 (sc1 agent atomics, ~700cy RT) to the
// XCD's shared L2 (~250cy RT):
//   publish: workgroup-scope relaxed stores (no sc1; write-through L1 -> L2;
//            r9-proven: WRITE_SIZE halved, FETCH at compulsory).
//   poll:    buffer_inv (vL1 invalidate) + volatile plain loads -> L1 miss
//            -> fresh local-L2 hit (r9-proven end-to-end via tag checks).
//   groups:  XCD-discovered (HW_REG_XCC_ID + slot atomicAdd; pigeonhole:
//            coop launch + 147.7KB LDS => 1 WG/CU => exactly 32 WGs/XCD).
//   safety:  tags in every data word; retry escalates to agent-scope (sc1)
//            loads after 64 rounds => wrong placement = slow pass, not hang.
// No flags, no fences, no extra barriers: SYNC2 (h/x staged), SYNC3 (spill),
// SYNC4 (__syncthreads; also orders red reuse + drains publish ~200cy L2).

typedef float  f32x4  __attribute__((ext_vector_type(4)));
typedef __bf16 bf16x8 __attribute__((ext_vector_type(8)));
typedef unsigned short u16x4 __attribute__((ext_vector_type(4)));
typedef unsigned long long u64;

#define TSEQ 512
#define INDIM 300
#define HID 512
#define ESC_ROUNDS 64

// LDS byte offsets
#define OWH 0          // W_hh slice: 64 rows x 1024B
#define OWI 65536      // W_ih slice: 64 rows x 640B (k>=300 zero)
#define OH  106496     // h tile: 16 rows x 1024B (batches 8..15 zero)
#define OX0 122880     // x tile buf0: 16 rows x 640B (pads zero)
#define OX1 133120     // x tile buf1
#define ORED 143360    // C spill: 64*17 f32 = 4352B
#define LDSZ 147712

__device__ __forceinline__ unsigned short f2bf(float f) {
    union { float f; unsigned u; } v; v.f = f;
    unsigned r = v.u + 0x7fffu + ((v.u >> 16) & 1u);  // RNE
    return (unsigned short)(r >> 16);
}
__device__ __forceinline__ float fsigmoid(float x) {
    return 1.0f / (1.0f + __expf(-x));
}
__device__ __forceinline__ float ftanh(float x) {
    float e = __expf(2.0f * x);
    return 1.0f - 2.0f / (e + 1.0f);
}

extern "C" __global__ __launch_bounds__(256, 1) void lstm_fused(
    const float* __restrict__ inputs,   // [512][64][300]
    const float* __restrict__ Wih,      // [2048][300]
    const float* __restrict__ Whh,      // [2048][512]
    const float* __restrict__ bih,      // [2048]
    const float* __restrict__ bhh,      // [2048]
    unsigned int* __restrict__ hcomm,   // [2][64][512] (tag<<16)|bf16
    unsigned int* __restrict__ slotcnt, // [8] per-XCD slot counters
    float* __restrict__ out)            // [64][512]
{
    __shared__ __align__(16) char lds[LDSZ];
    __shared__ int slot_sh;

    const int tid = threadIdx.x;

    // ---- discover XCD, claim slot (r7/r9-proven) ----
    int xcd;
    asm("s_getreg_b32 %0, hwreg(HW_REG_XCC_ID)" : "=s"(xcd));
    xcd &= 7;
    if (tid == 0) slot_sh = (int)atomicAdd(&slotcnt[xcd], 1u);

    // ---- zero pad-bearing LDS [OWI, LDSZ) = 82176 B = 5136 x 16B ----
    {
        f32x4 z = {0.0f, 0.0f, 0.0f, 0.0f};
        for (int n = 0; n < 21; ++n) {
            int i = n * 256 + tid;
            if (i < 5136)
                *reinterpret_cast<f32x4*>(lds + OWI + i * 16) = z;
        }
    }
    __syncthreads();
    const int grp = xcd;
    const int mw  = slot_sh & 31;

    // ---- stage W_hh slice (bf16, XOR-swizzled); wave = gate ----
    for (int n = 0; n < 32; ++n) {
        int i  = n * 256 + tid;
        int r  = i >> 7;
        int ic = i & 127;
        int q = r >> 4, jj = r & 15;
        const float4 w = *reinterpret_cast<const float4*>(
            Whh + ((size_t)(q * HID + mw * 16 + jj) * HID + ic * 4));
        u16x4 p = {f2bf(w.x), f2bf(w.y), f2bf(w.z), f2bf(w.w)};
        *reinterpret_cast<u16x4*>(lds + OWH + r * 1024 +
                                  ((ic * 8) ^ ((r & 7) << 4))) = p;
    }
    // ---- stage W_ih slice ----
    for (int n = 0; n < 19; ++n) {
        int i = n * 256 + tid;
        if (i < 4800) {
            int r  = i / 75;
            int ic = i - r * 75;
            int q = r >> 4, jj = r & 15;
            const float4 w = *reinterpret_cast<const float4*>(
                Wih + ((size_t)(q * HID + mw * 16 + jj) * INDIM + ic * 4));
            u16x4 p = {f2bf(w.x), f2bf(w.y), f2bf(w.z), f2bf(w.w)};
            *reinterpret_cast<u16x4*>(lds + OWI + r * 640 +
                                      ((ic * 8) ^ ((r & 7) << 4))) = p;
        }
    }

    // ---- per-thread MFMA roles ----
    const int lane = tid & 63;
    const int wv   = tid >> 6;
    const int arow = wv * 16 + (lane & 15);
    const int kb16 = (lane >> 4) << 4;
    const int amask = (arow & 7) << 4;
    const int aoffh = arow * 1024;
    const int aoffi = arow * 640;
    const int bcol  = lane & 15;
    const int bmask = (bcol & 7) << 4;
    const int boffh = bcol * 1024;
    const int boffi = bcol * 640;

    // assembly roles (tid < 128)
    const int aj = tid & 15;
    const int ab = tid >> 4;
    float bias0 = 0.f, bias1 = 0.f, bias2 = 0.f, bias3 = 0.f;
    if (tid < 128) {
        int hidx = mw * 16 + aj;
        bias0 = bih[0 * HID + hidx] + bhh[0 * HID + hidx];
        bias1 = bih[1 * HID + hidx] + bhh[1 * HID + hidx];
        bias2 = bih[2 * HID + hidx] + bhh[2 * HID + hidx];
        bias3 = bih[3 * HID + hidx] + bhh[3 * HID + hidx];
    }
    float cst = 0.0f;

    // x prefetch decomposition
    const int i0 = tid,       b0 = i0 / 75, c0 = i0 - b0 * 75;
    const int i1 = 256 + tid, b1 = i1 / 75, c1 = i1 - b1 * 75;
    const int i2 = 512 + tid, b2 = i2 / 75, c2 = i2 - b2 * 75;
    const bool has2 = (i2 < 600);

    float* red = reinterpret_cast<float*>(lds + ORED);

    // ---- prologue: stage x_0 into OX0 ----
    {
        const float* xb = inputs + (size_t)(grp * 8) * INDIM;
        float4 v0 = *reinterpret_cast<const float4*>(xb + (size_t)b0 * INDIM + c0 * 4);
        float4 v1 = *reinterpret_cast<const float4*>(xb + (size_t)b1 * INDIM + c1 * 4);
        u16x4 p0 = {f2bf(v0.x), f2bf(v0.y), f2bf(v0.z), f2bf(v0.w)};
        u16x4 p1 = {f2bf(v1.x), f2bf(v1.y), f2bf(v1.z), f2bf(v1.w)};
        *reinterpret_cast<u16x4*>(lds + OX0 + b0 * 640 + ((c0 * 8) ^ ((b0 & 7) << 4))) = p0;
        *reinterpret_cast<u16x4*>(lds + OX0 + b1 * 640 + ((c1 * 8) ^ ((b1 & 7) << 4))) = p1;
        if (has2) {
            float4 v2 = *reinterpret_cast<const float4*>(xb + (size_t)b2 * INDIM + c2 * 4);
            u16x4 p2 = {f2bf(v2.x), f2bf(v2.y), f2bf(v2.z), f2bf(v2.w)};
            *reinterpret_cast<u16x4*>(lds + OX0 + b2 * 640 + ((c2 * 8) ^ ((b2 & 7) << 4))) = p2;
        }
    }
    __syncthreads();   // weights + x_0 staged

#pragma unroll 1
    for (int t = 0; t < TSEQ; ++t) {
        const char* oxc = lds + OX0 + (t & 1) * 10240;

        // ---- (1) vL1 invalidate + issue 8 h poll loads (latency under MFMAs) ----
        u64 hv64[8];
        const u64* hc = reinterpret_cast<const u64*>(
            hcomm + (size_t)(t & 1) * 32768) + (size_t)grp * 2048 + tid;
        const volatile u64* hcv = reinterpret_cast<const volatile u64*>(hc);
        if (t > 0) {
            asm volatile("buffer_inv" ::: "memory");
#pragma unroll
            for (int b = 0; b < 8; ++b) hv64[b] = hcv[b * 256];
        }

        // ---- (2) issue x_{t+1} loads (after polls; vmcnt in-order) ----
        float4 xv0, xv1, xv2;
        if (t + 1 < TSEQ) {
            const float* xb = inputs + ((size_t)(t + 1) * 64 + grp * 8) * INDIM;
            xv0 = *reinterpret_cast<const float4*>(xb + (size_t)b0 * INDIM + c0 * 4);
            xv1 = *reinterpret_cast<const float4*>(xb + (size_t)b1 * INDIM + c1 * 4);
            if (has2)
                xv2 = *reinterpret_cast<const float4*>(xb + (size_t)b2 * INDIM + c2 * 4);
        }

        // ---- (3) x-part MFMAs (hide poll latency) ----
        f32x4 ac0 = {0.f, 0.f, 0.f, 0.f};
        f32x4 ac1 = {0.f, 0.f, 0.f, 0.f};
        f32x4 ac2 = {0.f, 0.f, 0.f, 0.f};
        f32x4 ac3 = {0.f, 0.f, 0.f, 0.f};
#pragma unroll
        for (int m = 0; m < 10; ++m) {
            bf16x8 a = *reinterpret_cast<const bf16x8*>(
                lds + OWI + aoffi + ((m * 64 + kb16) ^ amask));
            bf16x8 b = *reinterpret_cast<const bf16x8*>(
                oxc + boffi + ((m * 64 + kb16) ^ bmask));
            switch (m & 3) {
                case 0: ac0 = __builtin_amdgcn_mfma_f32_16x16x32_bf16(a, b, ac0, 0, 0, 0); break;
                case 1: ac1 = __builtin_amdgcn_mfma_f32_16x16x32_bf16(a, b, ac1, 0, 0, 0); break;
                case 2: ac2 = __builtin_amdgcn_mfma_f32_16x16x32_bf16(a, b, ac2, 0, 0, 0); break;
                default: ac3 = __builtin_amdgcn_mfma_f32_16x16x32_bf16(a, b, ac3, 0, 0, 0); break;
            }
        }

        // ---- (4) tag check; parallel masked retry (inv+reload), escalate ----
        if (t > 0) {
            const u64 expect = ((u64)t << 48) | ((u64)t << 16);
            const u64 tmask  = 0xffff0000ffff0000ull;
            unsigned pend = 0;
#pragma unroll
            for (int b = 0; b < 8; ++b)
                if ((hv64[b] & tmask) != expect) pend |= 1u << b;
            int rounds = 0;
            while (pend) {
                __builtin_amdgcn_s_sleep(1);
                if (rounds < ESC_ROUNDS) {
                    asm volatile("buffer_inv" ::: "memory");
#pragma unroll
                    for (int b = 0; b < 8; ++b)
                        if (pend & (1u << b)) hv64[b] = hcv[b * 256];
                } else {   // safety net: sc1 probes peer L2s / L3
#pragma unroll
                    for (int b = 0; b < 8; ++b)
                        if (pend & (1u << b))
                            hv64[b] = __hip_atomic_load(hc + b * 256, __ATOMIC_RELAXED,
                                                        __HIP_MEMORY_SCOPE_AGENT);
                }
#pragma unroll
                for (int b = 0; b < 8; ++b)
                    if ((hv64[b] & tmask) == expect) pend &= ~(1u << b);
                ++rounds;
            }
#pragma unroll
            for (int b = 0; b < 8; ++b) {
                unsigned pk = (unsigned)(hv64[b] & 0xffffu) |
                              ((unsigned)((hv64[b] >> 32) & 0xffffu) << 16);
                *reinterpret_cast<unsigned*>(
                    lds + OH + b * 1024 + ((tid * 4) ^ ((b & 7) << 4))) = pk;
            }
        }

        // ---- (5) write x_{t+1} into the other OX buffer ----
        if (t + 1 < TSEQ) {
            char* oxn = lds + OX0 + ((t + 1) & 1) * 10240;
            u16x4 p0 = {f2bf(xv0.x), f2bf(xv0.y), f2bf(xv0.z), f2bf(xv0.w)};
            u16x4 p1 = {f2bf(xv1.x), f2bf(xv1.y), f2bf(xv1.z), f2bf(xv1.w)};
            *reinterpret_cast<u16x4*>(oxn + b0 * 640 + ((c0 * 8) ^ ((b0 & 7) << 4))) = p0;
            *reinterpret_cast<u16x4*>(oxn + b1 * 640 + ((c1 * 8) ^ ((b1 & 7) << 4))) = p1;
            if (has2) {
                u16x4 p2 = {f2bf(xv2.x), f2bf(xv2.y), f2bf(xv2.z), f2bf(xv2.w)};
                *reinterpret_cast<u16x4*>(oxn + b2 * 640 + ((c2 * 8) ^ ((b2 & 7) << 4))) = p2;
            }
        }
        __syncthreads();   // SYNC2: h(t)/x(t+1) staged, prior-step reads done

        // ---- (6) h-part MFMAs ----
        if (t > 0) {
#pragma unroll
            for (int m = 0; m < 16; ++m) {
                bf16x8 a = *reinterpret_cast<const bf16x8*>(
                    lds + OWH + aoffh + ((m * 64 + kb16) ^ amask));
                bf16x8 b = *reinterpret_cast<const bf16x8*>(
                    lds + OH + boffh + ((m * 64 + kb16) ^ bmask));
                switch (m & 3) {
                    case 0: ac0 = __builtin_amdgcn_mfma_f32_16x16x32_bf16(a, b, ac0, 0, 0, 0); break;
                    case 1: ac1 = __builtin_amdgcn_mfma_f32_16x16x32_bf16(a, b, ac1, 0, 0, 0); break;
                    case 2: ac2 = __builtin_amdgcn_mfma_f32_16x16x32_bf16(a, b, ac2, 0, 0, 0); break;
                    default: ac3 = __builtin_amdgcn_mfma_f32_16x16x32_bf16(a, b, ac3, 0, 0, 0); break;
                }
            }
        }
        f32x4 accv = (ac0 + ac1) + (ac2 + ac3);

        // ---- (7) spill C (m89 layout: col=lane&15, row=(lane>>4)*4+reg) ----
        {
            int rbase = (wv * 16 + ((lane >> 4) << 2)) * 17 + bcol;
            red[rbase + 0]  = accv.x;
            red[rbase + 17] = accv.y;
            red[rbase + 34] = accv.z;
            red[rbase + 51] = accv.w;
        }
        __syncthreads();   // SYNC3: spill done

        // ---- (8) gates + cell update + workgroup-scope publish (stays in L2) ----
        if (tid < 128) {
            float gi = bias0 + red[(0 * 16 + aj) * 17 + ab];
            float gf = bias1 + red[(1 * 16 + aj) * 17 + ab];
            float gg = bias2 + red[(2 * 16 + aj) * 17 + ab];
            float go = bias3 + red[(3 * 16 + aj) * 17 + ab];
            float ig = fsigmoid(gi);
            float fg = fsigmoid(gf);
            float cg = ftanh(gg);
            float og = fsigmoid(go);
            cst = fg * cst + ig * cg;
            float hv = og * ftanh(cst);
            if (t == TSEQ - 1) {
                out[(size_t)(grp * 8 + ab) * HID + mw * 16 + aj] = hv;
            } else {
                unsigned word = ((unsigned)(t + 1) << 16) | (unsigned)f2bf(hv);
                __hip_atomic_store(
                    hcomm + (size_t)((t + 1) & 1) * 32768 +
                        (size_t)(grp * 8 + ab) * 512 + mw * 16 + aj,
                    word, __ATOMIC_RELAXED, __HIP_MEMORY_SCOPE_WORKGROUP);
            }
        }
        __syncthreads();   // SYNC4: red reuse ordered; publish drained (~L2 RT)
    }
}

extern "C" void kernel_launch(void* const* d_in, const int* in_sizes, int n_in,
                              void* d_out, int out_size, void* d_ws, size_t ws_size,
                              hipStream_t stream) {
    const float* inputs = (const float*)d_in[0];
    const float* Wih    = (const float*)d_in[1];
    const float* Whh    = (const float*)d_in[2];
    const float* bih    = (const float*)d_in[3];
    const float* bhh    = (const float*)d_in[4];
    float* out = (float*)d_out;

    unsigned int* hcomm   = (unsigned int*)d_ws;                    // 256 KB
    unsigned int* slotcnt = (unsigned int*)((char*)d_ws + 262144);  // 32 B

    hipMemsetAsync(d_ws, 0, 262144 + 64, stream);

    void* args[] = {(void*)&inputs, (void*)&Wih, (void*)&Whh, (void*)&bih,
                    (void*)&bhh,    (void*)&hcomm, (void*)&slotcnt, (void*)&out};
    hipLaunchCooperativeKernel(reinterpret_cast<void*>(lstm_fused),
                               dim3(256), dim3(256), args, 0, stream);
}